// Round 5
// baseline (328.135 us; speedup 1.0000x reference)
//
#include <hip/hip_runtime.h>

#define THREADS 256
#define SPT 2
#define SAMPLES_PER_BLOCK (THREADS * SPT)

__device__ __forceinline__ float fast_sigmoid(float v) {
    float e = __expf(-v);
    return __builtin_amdgcn_rcpf(1.0f + e);
}

__global__ __launch_bounds__(THREADS) void olcnn_kernel(
    const float* __restrict__ x,
    const float* __restrict__ Wc, const float* __restrict__ bc,
    const float* __restrict__ Wh, const float* __restrict__ bh,
    const float* __restrict__ Wm, const float* __restrict__ bm,
    const float* __restrict__ Wo, const float* __restrict__ bo,
    float* __restrict__ out)
{
    // COMPACT-CODE version of round 4: G and j loops are runtime (not
    // unrolled) so the kernel body is ~3 KB instead of ~30 KB. Theory: all
    // previous rounds were I$-thrash-bound (time invariant at ~100 us across
    // totally different data paths). Memory path identical to round 4.
    const int tid  = threadIdx.x;
    const int wave = tid >> 6, lane = tid & 63;
    const int s0 = blockIdx.x * SAMPLES_PER_BLOCK + wave * (64 * SPT) + lane;
    const int s1 = s0 + 64;
    const float* xA = x + s0 * 81;
    const float* xB = x + s1 * 81;

    float rA0 = 0.f, rA1 = 0.f, rA2 = 0.f, rA3 = 0.f;
    float rB0 = 0.f, rB1 = 0.f, rB2 = 0.f, rB3 = 0.f;

    #pragma clang loop unroll(disable)
    for (int G = 0; G < 3; ++G) {
        // middle-layer accumulators, folded incrementally over j
        float mA[4], mB[4];
        #pragma unroll
        for (int n4 = 0; n4 < 4; ++n4) { mA[n4] = bm[G * 4 + n4]; mB[n4] = mA[n4]; }

        #pragma clang loop unroll(disable)
        for (int j = 0; j < 3; ++j) {
            const int g = G * 3 + j;                 // wave-uniform
            const float* wc = Wc + g * 81;

            float p0[9], p1[9];
            #pragma unroll
            for (int pr = 0; pr < 3; ++pr)
                #pragma unroll
                for (int pc = 0; pc < 3; ++pc) {
                    const int off = G * 27 + pr * 9 + j * 3 + pc;
                    p0[pr * 3 + pc] = xA[off];
                    p1[pr * 3 + pc] = xB[off];
                }

            float f0[9], f1[9];
            #pragma unroll
            for (int k = 0; k < 9; ++k) {
                float a0 = bc[g * 9 + k], a1 = a0;
                #pragma unroll
                for (int p = 0; p < 9; ++p) {
                    const float w = wc[k * 9 + p];
                    a0 = fmaf(p0[p], w, a0);
                    a1 = fmaf(p1[p], w, a1);
                }
                f0[k] = fast_sigmoid(a0);
                f1[k] = fast_sigmoid(a1);
            }

            #pragma unroll
            for (int n = 0; n < 3; ++n) {
                float a0 = bh[g * 3 + n], a1 = a0;
                #pragma unroll
                for (int p = 0; p < 9; ++p) {
                    const float w = Wh[(g * 3 + n) * 9 + p];
                    a0 = fmaf(f0[p], w, a0);
                    a1 = fmaf(f1[p], w, a1);
                }
                const float h0 = fast_sigmoid(a0);
                const float h1 = fast_sigmoid(a1);
                #pragma unroll
                for (int n4 = 0; n4 < 4; ++n4) {
                    const float w = Wm[(G * 4 + n4) * 9 + j * 3 + n];
                    mA[n4] = fmaf(h0, w, mA[n4]);
                    mB[n4] = fmaf(h1, w, mB[n4]);
                }
            }
        }

        #pragma unroll
        for (int n4 = 0; n4 < 4; ++n4) {
            mA[n4] = fast_sigmoid(mA[n4]);
            mB[n4] = fast_sigmoid(mB[n4]);
        }

        // outputs reading middle group G: c = G always, plus c = 3 when G == 0
        float oA = bo[G], oB = oA;
        float qA = bo[3], qB = qA;
        #pragma unroll
        for (int p = 0; p < 4; ++p) {
            const float wg = Wo[G * 4 + p];
            const float w3 = Wo[12 + p];
            oA = fmaf(mA[p], wg, oA);
            oB = fmaf(mB[p], wg, oB);
            qA = fmaf(mA[p], w3, qA);
            qB = fmaf(mB[p], w3, qB);
        }
        rA0 = (G == 0) ? oA : rA0;  rB0 = (G == 0) ? oB : rB0;
        rA1 = (G == 1) ? oA : rA1;  rB1 = (G == 1) ? oB : rB1;
        rA2 = (G == 2) ? oA : rA2;  rB2 = (G == 2) ? oB : rB2;
        rA3 = (G == 0) ? qA : rA3;  rB3 = (G == 0) ? qB : rB3;
    }

    float4 oA4, oB4;
    oA4.x = rA0; oA4.y = rA1; oA4.z = rA2; oA4.w = rA3;
    oB4.x = rB0; oB4.y = rB1; oB4.z = rB2; oB4.w = rB3;
    ((float4*)out)[s0] = oA4;
    ((float4*)out)[s1] = oB4;
}

extern "C" void kernel_launch(void* const* d_in, const int* in_sizes, int n_in,
                              void* d_out, int out_size, void* d_ws, size_t ws_size,
                              hipStream_t stream) {
    const float* x  = (const float*)d_in[0];
    const float* Wc = (const float*)d_in[1];
    const float* bc = (const float*)d_in[2];
    const float* Wh = (const float*)d_in[3];
    const float* bh = (const float*)d_in[4];
    const float* Wm = (const float*)d_in[5];
    const float* bm = (const float*)d_in[6];
    const float* Wo = (const float*)d_in[7];
    const float* bo = (const float*)d_in[8];
    float* out = (float*)d_out;

    const int B = in_sizes[0] / 81;                    // 524288
    const int blocks = B / SAMPLES_PER_BLOCK;          // 1024 (exact)
    olcnn_kernel<<<blocks, THREADS, 0, stream>>>(x, Wc, bc, Wh, bh, Wm, bm,
                                                 Wo, bo, out);
}

// Round 6
// 272.891 us; speedup vs baseline: 1.2024x; 1.2024x over previous
//
#include <hip/hip_runtime.h>

#define THREADS 256

__device__ __forceinline__ float fast_sigmoid(float v) {
    float e = __expf(-v);
    return __builtin_amdgcn_rcpf(1.0f + e);
}

// 1 sample/thread, NO LDS, load-all-then-compute: all 81 sample floats are
// loaded into registers up front (one vmcnt window, ~21 merged loads, 20.7 KB
// in flight per wave), then ~2500 cy of pure compute with weights in scalar
// K$. __launch_bounds__(256,4) caps VGPR at 128 -> 4 waves/SIMD.
__global__ __launch_bounds__(THREADS, 4) void olcnn_kernel(
    const float* __restrict__ x,
    const float* __restrict__ Wc, const float* __restrict__ bc,
    const float* __restrict__ Wh, const float* __restrict__ bh,
    const float* __restrict__ Wm, const float* __restrict__ bm,
    const float* __restrict__ Wo, const float* __restrict__ bo,
    float* __restrict__ out)
{
    const int s = blockIdx.x * THREADS + threadIdx.x;   // lane-contiguous samples
    const float* xs = x + s * 81;

    // Prefetch the whole sample. Consecutive lanes read consecutive 324-B
    // runs -> the wave's 20.7 KB footprint is contiguous, every line fully
    // consumed. LLVM merges these into dwordx4/x2 clusters issued up front.
    float pix[81];
    #pragma unroll
    for (int i = 0; i < 81; ++i) pix[i] = xs[i];

    float res[4];

    #pragma unroll
    for (int G = 0; G < 3; ++G) {
        float hbuf[9];
        #pragma unroll
        for (int j = 0; j < 3; ++j) {              // conv patch g = (G, j)
            const int g = G * 3 + j;
            float feat[9];
            #pragma unroll
            for (int k = 0; k < 9; ++k) {          // 9 independent chains -> ILP
                float acc = bc[g * 9 + k];
                #pragma unroll
                for (int pr = 0; pr < 3; ++pr)
                    #pragma unroll
                    for (int pc = 0; pc < 3; ++pc)
                        acc = fmaf(pix[G * 27 + pr * 9 + j * 3 + pc],
                                   Wc[(g * 9 + k) * 9 + pr * 3 + pc], acc);
                feat[k] = fast_sigmoid(acc);
            }
            #pragma unroll
            for (int n = 0; n < 3; ++n) {
                float acc = bh[g * 3 + n];
                #pragma unroll
                for (int p = 0; p < 9; ++p)
                    acc = fmaf(feat[p], Wh[(g * 3 + n) * 9 + p], acc);
                hbuf[j * 3 + n] = fast_sigmoid(acc);
            }
        }

        float m[4];
        #pragma unroll
        for (int n = 0; n < 4; ++n) {
            float acc = bm[G * 4 + n];
            #pragma unroll
            for (int p = 0; p < 9; ++p)
                acc = fmaf(hbuf[p], Wm[(G * 4 + n) * 9 + p], acc);
            m[n] = fast_sigmoid(acc);
        }

        // outputs reading middle group G (c % 3 == G): c = G, plus c = 3 @ G = 0
        {
            float acc = bo[G];
            #pragma unroll
            for (int p = 0; p < 4; ++p)
                acc = fmaf(m[p], Wo[G * 4 + p], acc);
            res[G] = acc;
        }
        if (G == 0) {
            float acc = bo[3];
            #pragma unroll
            for (int p = 0; p < 4; ++p)
                acc = fmaf(m[p], Wo[3 * 4 + p], acc);
            res[3] = acc;
        }
    }

    float4 o;
    o.x = res[0]; o.y = res[1]; o.z = res[2]; o.w = res[3];
    ((float4*)out)[s] = o;                         // coalesced 16B/lane store
}

extern "C" void kernel_launch(void* const* d_in, const int* in_sizes, int n_in,
                              void* d_out, int out_size, void* d_ws, size_t ws_size,
                              hipStream_t stream) {
    const float* x  = (const float*)d_in[0];
    const float* Wc = (const float*)d_in[1];
    const float* bc = (const float*)d_in[2];
    const float* Wh = (const float*)d_in[3];
    const float* bh = (const float*)d_in[4];
    const float* Wm = (const float*)d_in[5];
    const float* bm = (const float*)d_in[6];
    const float* Wo = (const float*)d_in[7];
    const float* bo = (const float*)d_in[8];
    float* out = (float*)d_out;

    const int B = in_sizes[0] / 81;                // 524288
    const int blocks = B / THREADS;                // 2048 (exact)
    olcnn_kernel<<<blocks, THREADS, 0, stream>>>(x, Wc, bc, Wh, bh, Wm, bm,
                                                 Wo, bo, out);
}